// Round 16
// baseline (319.141 us; speedup 1.0000x reference)
//
#include <hip/hip_runtime.h>
#include <hip/hip_bf16.h>
#include <stdint.h>

// GroupCommunication fused: 65536 tok x 1024 ch; 16 blocks x 64; 2 heads x 32.
// R16 = R9 made persistent with ZERO added live state. Grid 256 (1 WG/CU,
// 160KB dynamic LDS), 1024 thr (16 waves, one g per wave), loop over NT=8
// tiles of 32 tokens. All barriers are LGKM-ONLY (s_waitcnt lgkmcnt(0) +
// s_barrier): out-stores of tile i float across tile i+1's phases and drain
// only at kernel end -- removes the per-generation store-drain + WG retire
// + launch that cost ~5-10us/generation (R13 tried this but spilled from
// +16 prefetch regs; here x is loaded at span start exactly like R9, so the
// live set is R9's ~52 VGPR).
// Per tile: XLOAD+PH1(0) |B1| PH2->a0 |B2| PH1(1) |B3| LOADF+PH2->a1 |B4|
//           PH3+store -> loop (a0/a1 WAR separated by next B1/B2).

typedef __attribute__((ext_vector_type(8))) short bf16x8;
typedef __attribute__((ext_vector_type(4))) float f32x4;

#define NTOK   65536
#define DM     1024
#define TILE   32
#define NT     8                       // tiles per WG; grid = NTOK/(TILE*NT) = 256
#define QSCALE 0.17677669529663687f    // 32^-0.5
#define LOG2E  1.4426950408889634f

// lgkm-only barrier: orders all LDS traffic across waves; global loads are
// synchronized at their use sites by compiler-inserted vmcnt; stores never
// need draining (no same-WG read-back of out).
#define BAR() do {                                        \
  asm volatile("s_waitcnt lgkmcnt(0)" ::: "memory");      \
  __builtin_amdgcn_s_barrier();                           \
} while (0)

static __device__ __forceinline__ unsigned short f2bf(float f) {
  union { __hip_bfloat16 h; unsigned short s; } cv;
  cv.h = __float2bfloat16(f);          // RNE
  return cv.s;
}

static __device__ __forceinline__ unsigned int pk2(float a, float b) {
  return (unsigned int)f2bf(a) | ((unsigned int)f2bf(b) << 16);
}

static __device__ __forceinline__ bf16x8 pack8(float4 a, float4 b) {
  bf16x8 r;
  r[0] = (short)f2bf(a.x); r[1] = (short)f2bf(a.y);
  r[2] = (short)f2bf(a.z); r[3] = (short)f2bf(a.w);
  r[4] = (short)f2bf(b.x); r[5] = (short)f2bf(b.y);
  r[6] = (short)f2bf(b.z); r[7] = (short)f2bf(b.w);
  return r;
}

union FragCast { uint4 u4; bf16x8 v; uint2 u2[2]; unsigned int u[4]; };

// ---------------------------------------------------------------------------
// Prologue: pack wq(scaled),wk,wv,wf fp32 [g][i][o] -> bf16 fragment stream.
// frag elem j = W[k = kk*32 + 8*(lane>>4) + j][o = nf*16 + (lane&15)].
// A- and B-side consumers always use the identical (lane,j)->k map.
// ---------------------------------------------------------------------------
__global__ void build_wfrag(const float* __restrict__ wq, const float* __restrict__ wk,
                            const float* __restrict__ wv, const float* __restrict__ wf,
                            uint4* __restrict__ wfrag) {
  int tid = blockIdx.x * 256 + threadIdx.x;
  if (tid >= 4 * 16 * 2 * 4 * 64) return;
  int lane =  tid        & 63;
  int nf   = (tid >> 6)  & 3;
  int kk   = (tid >> 8)  & 1;
  int g    = (tid >> 9)  & 15;
  int mat  =  tid >> 13;
  const float* w = (mat == 0) ? wq : (mat == 1) ? wk : (mat == 2) ? wv : wf;
  float sc = (mat == 0) ? QSCALE : 1.0f;
  int o  = nf * 16 + (lane & 15);
  int kb = kk * 32 + 8 * (lane >> 4);
  unsigned int packed[4];
#pragma unroll
  for (int jj = 0; jj < 4; ++jj) {
    unsigned short lo = f2bf(w[(g * 64 + kb + 2 * jj    ) * 64 + o] * sc);
    unsigned short hi = f2bf(w[(g * 64 + kb + 2 * jj + 1) * 64 + o] * sc);
    packed[jj] = (unsigned int)lo | ((unsigned int)hi << 16);
  }
  uint4 u; u.x = packed[0]; u.y = packed[1]; u.z = packed[2]; u.w = packed[3];
  wfrag[tid] = u;
}

// ---------------------------------------------------------------------------
// Phase helper macros (h_ / nf2_ literals; named frags only -> registers).
// Identical to the verified R9 kernel.
// ---------------------------------------------------------------------------

// q/k: swapped orientation. D[o][t]: col t = 16m+lr, rows o = nf*16+4lq+r.
#define QK_STORE(fA_, fB_, nf2_, h_, bp_, bsc_, dst_) do {                    \
  const int nf = 2 * (h_) + (nf2_);                                           \
  float4 b4 = *(const float4*)&(bp_)[g * 64 + nf * 16 + 4 * lq];              \
  _Pragma("unroll")                                                           \
  for (int m = 0; m < 2; ++m) {                                               \
    f32x4 a1 = {b4.x * (bsc_), b4.y * (bsc_), b4.z * (bsc_), b4.w * (bsc_)};  \
    a1 = __builtin_amdgcn_mfma_f32_16x16x32_bf16((fA_).v, afr[m][0], a1, 0, 0, 0); \
    a1 = __builtin_amdgcn_mfma_f32_16x16x32_bf16((fB_).v, afr[m][1], a1, 0, 0, 0); \
    uint2 w2; w2.x = pk2(a1[0], a1[1]); w2.y = pk2(a1[2], a1[3]);             \
    const int blk = (16 * (2 * (nf2_) + (lq >> 1)) + g) ^ (lr & 7);           \
    *(uint2*)&(dst_)[(16 * m + lr) * 512 + blk * 8 + 4 * (lq & 1)] = w2;      \
  }                                                                           \
} while (0)

// v: original orientation. D[t][o]: rows t = 16m+4lq+r, col d_h = nf2*16+lr;
// stream pos encodes (f=g, d): pos = 64*(g>>2) + 4*d + (g&3).
#define V_STORE(fA_, fB_, nf2_, h_) do {                                      \
  const int nf = 2 * (h_) + (nf2_);                                           \
  const float bias = bv[g * 64 + nf * 16 + lr];                               \
  const int L = 16 * (g >> 2) + lr;                                           \
  const int jj = g & 3;                                                       \
  _Pragma("unroll")                                                           \
  for (int m = 0; m < 2; ++m) {                                               \
    f32x4 a1 = {bias, bias, bias, bias};                                      \
    a1 = __builtin_amdgcn_mfma_f32_16x16x32_bf16(afr[m][0], (fA_).v, a1, 0, 0, 0); \
    a1 = __builtin_amdgcn_mfma_f32_16x16x32_bf16(afr[m][1], (fB_).v, a1, 0, 0, 0); \
    _Pragma("unroll")                                                         \
    for (int r = 0; r < 4; ++r)                                               \
      s_v[((16 * m + 4 * lq + r) * 2 + (nf2_)) * 256 + L * 4 + jj] = f2bf(a1[r]); \
  }                                                                           \
} while (0)

#define PH1(h_) do {                                                          \
  FragCast q0a, q0b, q1a, q1b, k0a, k0b, k1a, k1b, v0a, v0b, v1a, v1b;        \
  q0a.u4 = wfrag[(((0 * 16 + g) * 2 + 0) * 4 + 2 * (h_)    ) * 64 + lane];    \
  q0b.u4 = wfrag[(((0 * 16 + g) * 2 + 1) * 4 + 2 * (h_)    ) * 64 + lane];    \
  q1a.u4 = wfrag[(((0 * 16 + g) * 2 + 0) * 4 + 2 * (h_) + 1) * 64 + lane];    \
  q1b.u4 = wfrag[(((0 * 16 + g) * 2 + 1) * 4 + 2 * (h_) + 1) * 64 + lane];    \
  k0a.u4 = wfrag[(((1 * 16 + g) * 2 + 0) * 4 + 2 * (h_)    ) * 64 + lane];    \
  k0b.u4 = wfrag[(((1 * 16 + g) * 2 + 1) * 4 + 2 * (h_)    ) * 64 + lane];    \
  k1a.u4 = wfrag[(((1 * 16 + g) * 2 + 0) * 4 + 2 * (h_) + 1) * 64 + lane];    \
  k1b.u4 = wfrag[(((1 * 16 + g) * 2 + 1) * 4 + 2 * (h_) + 1) * 64 + lane];    \
  v0a.u4 = wfrag[(((2 * 16 + g) * 2 + 0) * 4 + 2 * (h_)    ) * 64 + lane];    \
  v0b.u4 = wfrag[(((2 * 16 + g) * 2 + 1) * 4 + 2 * (h_)    ) * 64 + lane];    \
  v1a.u4 = wfrag[(((2 * 16 + g) * 2 + 0) * 4 + 2 * (h_) + 1) * 64 + lane];    \
  v1b.u4 = wfrag[(((2 * 16 + g) * 2 + 1) * 4 + 2 * (h_) + 1) * 64 + lane];    \
  QK_STORE(q0a, q0b, 0, h_, bq, QSCALE, s_q);                                 \
  QK_STORE(q1a, q1b, 1, h_, bq, QSCALE, s_q);                                 \
  QK_STORE(k0a, k0b, 0, h_, bk, 1.0f,   s_k);                                 \
  QK_STORE(k1a, k1b, 1, h_, bk, 1.0f,   s_k);                                 \
  V_STORE(v0a, v0b, 0, h_);                                                   \
  V_STORE(v1a, v1b, 1, h_);                                                   \
} while (0)

// PH2: QK^T + softmax + PV for t = g and t = g+16 of the current head.
#define PH2(ATT_) do {                                                        \
  _Pragma("unroll")                                                           \
  for (int tt = 0; tt < 2; ++tt) {                                            \
    const int t = g + 16 * tt;                                                \
    f32x4 zero = {0.f, 0.f, 0.f, 0.f};                                        \
    FragCast qa, ka;                                                          \
    const int blk = lane ^ (t & 7);                                           \
    qa.u4 = *(const uint4*)&s_q[t * 512 + blk * 8];                           \
    ka.u4 = *(const uint4*)&s_k[t * 512 + blk * 8];                           \
    /* D[f][g]: col g=lr, rows f=4lq+r (K=32 = full head dim) */              \
    f32x4 sc4 = __builtin_amdgcn_mfma_f32_16x16x32_bf16(ka.v, qa.v, zero, 0, 0, 0); \
    float m = fmaxf(fmaxf(sc4[0], sc4[1]), fmaxf(sc4[2], sc4[3]));            \
    m = fmaxf(m, __shfl_xor(m, 16));                                          \
    m = fmaxf(m, __shfl_xor(m, 32));                                          \
    float p0 = exp2f((sc4[0] - m) * LOG2E);                                   \
    float p1 = exp2f((sc4[1] - m) * LOG2E);                                   \
    float p2 = exp2f((sc4[2] - m) * LOG2E);                                   \
    float p3 = exp2f((sc4[3] - m) * LOG2E);                                   \
    float s = p0 + p1 + p2 + p3;                                              \
    s += __shfl_xor(s, 16);                                                   \
    s += __shfl_xor(s, 32);                                                   \
    const float inv = __fdividef(1.0f, s);                                    \
    FragCast pa;               /* P[g=lr][f=4lq+jj] at slots jj 0..3 */       \
    pa.u[0] = pk2(p0 * inv, p1 * inv);                                        \
    pa.u[1] = pk2(p2 * inv, p3 * inv);                                        \
    pa.u[2] = 0; pa.u[3] = 0;                                                 \
    FragCast va0, va1;         /* V[f=4lq+jj][d=nf*16+lr] at slots jj 0..3 */ \
    va0.u2[0] = *(const uint2*)&s_v[(t * 2 + 0) * 256 + lane * 4];            \
    va0.u[2] = 0; va0.u[3] = 0;                                               \
    va1.u2[0] = *(const uint2*)&s_v[(t * 2 + 1) * 256 + lane * 4];            \
    va1.u[2] = 0; va1.u[3] = 0;                                               \
    /* D[d][g]: col g=lr, rows d=nf*16+4lq+r */                               \
    f32x4 oo0 = __builtin_amdgcn_mfma_f32_16x16x32_bf16(va0.v, pa.v, zero, 0, 0, 0); \
    f32x4 oo1 = __builtin_amdgcn_mfma_f32_16x16x32_bf16(va1.v, pa.v, zero, 0, 0, 0); \
    uint2 w20; w20.x = pk2(oo0[0], oo0[1]); w20.y = pk2(oo0[2], oo0[3]);      \
    const int ab0 = (16 * (0 + (lq >> 1)) + lr) ^ (t & 7);                    \
    *(uint2*)&(ATT_)[t * 512 + ab0 * 8 + 4 * (lq & 1)] = w20;                 \
    uint2 w21; w21.x = pk2(oo1[0], oo1[1]); w21.y = pk2(oo1[2], oo1[3]);      \
    const int ab1 = (16 * (2 + (lq >> 1)) + lr) ^ (t & 7);                    \
    *(uint2*)&(ATT_)[t * 512 + ab1 * 8 + 4 * (lq & 1)] = w21;                 \
  }                                                                           \
} while (0)

#define LOADF() do {                                                          \
  f0n0.u4 = wfrag[(((3 * 16 + g) * 2 + 0) * 4 + 0) * 64 + lane];              \
  f0n1.u4 = wfrag[(((3 * 16 + g) * 2 + 0) * 4 + 1) * 64 + lane];              \
  f0n2.u4 = wfrag[(((3 * 16 + g) * 2 + 0) * 4 + 2) * 64 + lane];              \
  f0n3.u4 = wfrag[(((3 * 16 + g) * 2 + 0) * 4 + 3) * 64 + lane];              \
  f1n0.u4 = wfrag[(((3 * 16 + g) * 2 + 1) * 4 + 0) * 64 + lane];              \
  f1n1.u4 = wfrag[(((3 * 16 + g) * 2 + 1) * 4 + 1) * 64 + lane];              \
  f1n2.u4 = wfrag[(((3 * 16 + g) * 2 + 1) * 4 + 2) * 64 + lane];              \
  f1n3.u4 = wfrag[(((3 * 16 + g) * 2 + 1) * 4 + 3) * 64 + lane];              \
} while (0)

#define PH3_NF(f0_, f1_, nf_, m_, aa0_, aa1_) do {                            \
  float4 b4 = *(const float4*)&bfb[g * 64 + (nf_) * 16 + 4 * lq];             \
  f32x4 a1 = {b4.x, b4.y, b4.z, b4.w};                                        \
  a1 = __builtin_amdgcn_mfma_f32_16x16x32_bf16((f0_).v, (aa0_).v, a1, 0, 0, 0); \
  a1 = __builtin_amdgcn_mfma_f32_16x16x32_bf16((f1_).v, (aa1_).v, a1, 0, 0, 0); \
  float4 o4; o4.x = a1[0]; o4.y = a1[1]; o4.z = a1[2]; o4.w = a1[3];          \
  *(float4*)&out[(tok0 + 16 * (m_) + lr) * DM + g * 64 + (nf_) * 16 + 4 * lq] = o4; \
} while (0)

#define PH3() do {                                                            \
  const int blk3 = (16 * lq + g) ^ (lr & 7);                                  \
  _Pragma("unroll")                                                           \
  for (int m = 0; m < 2; ++m) {                                               \
    FragCast aa0, aa1;         /* att[t=16m+lr][g][d_h=8lq+j], per head */    \
    aa0.u4 = *(const uint4*)&s_a0[(16 * m + lr) * 512 + blk3 * 8];            \
    aa1.u4 = *(const uint4*)&s_a1[(16 * m + lr) * 512 + blk3 * 8];            \
    PH3_NF(f0n0, f1n0, 0, m, aa0, aa1);                                       \
    PH3_NF(f0n1, f1n1, 1, m, aa0, aa1);                                       \
    PH3_NF(f0n2, f1n2, 2, m, aa0, aa1);                                       \
    PH3_NF(f0n3, f1n3, 3, m, aa0, aa1);                                       \
  }                                                                           \
} while (0)

// ---------------------------------------------------------------------------
__global__ __launch_bounds__(1024)
void fused_pers9(const float* __restrict__ x,
                 const float* __restrict__ bq, const float* __restrict__ bk,
                 const float* __restrict__ bv, const float* __restrict__ bfb,
                 const uint4* __restrict__ wfrag,
                 float* __restrict__ out) {
  // Dynamic LDS, 160KB: five 32KB buffers.
  // q/k/a0/a1: [t(32)][blk(64)] x 16B, blk key ^(t&7).
  // v: [(t*2+nf2)][256 shorts] stream, pos = 64*(g>>2)+4*d+(g&3).
  extern __shared__ __align__(16) unsigned short sm[];
  unsigned short* const s_q  = sm;
  unsigned short* const s_k  = sm + 16384;
  unsigned short* const s_v  = sm + 32768;
  unsigned short* const s_a0 = sm + 49152;
  unsigned short* const s_a1 = sm + 65536;

  const int tid  = threadIdx.x;
  const int g    = tid >> 6;      // 16 waves: wave = g (PH1/PH3), t-base (PH2)
  const int lane = tid & 63;
  const int lr   = lane & 15;
  const int lq   = lane >> 4;
  const long base = (long)blockIdx.x * (NT * TILE);

  FragCast f0n0, f0n1, f0n2, f0n3, f1n0, f1n1, f1n2, f1n3;  // PH3 weights

  for (int it = 0; it < NT; ++it) {
    const long tok0 = base + (long)it * TILE;

    // x fragments for this tile (transient float4s die into afr immediately
    // -- no cross-span staging registers; this is what kept R9 at 52 VGPR)
    bf16x8 afr[2][2];
#pragma unroll
    for (int m = 0; m < 2; ++m) {
      const float* xr = x + (tok0 + 16 * m + lr) * DM + g * 64;
#pragma unroll
      for (int kk = 0; kk < 2; ++kk) {
        const float* p = xr + kk * 32 + 8 * lq;
        afr[m][kk] = pack8(*(const float4*)p, *(const float4*)(p + 4));
      }
    }

    PH1(0);
    BAR();                            // B1 (lgkm-only)
    PH2(s_a0);
    BAR();                            // B2
    PH1(1);
    BAR();                            // B3
    LOADF();                          // f-frags hide under PH2(1)
    PH2(s_a1);
    BAR();                            // B4
    PH3();                            // stores float across next tile's phases
    // loop-back: PH1(0) writes s_q/k/v (last read before B4); next PH2's
    // a0/a1 writes are separated from this PH3's reads by next B1/B2.
  }
}

// ---------------------------------------------------------------------------
extern "C" void kernel_launch(void* const* d_in, const int* in_sizes, int n_in,
                              void* d_out, int out_size, void* d_ws, size_t ws_size,
                              hipStream_t stream) {
  const float* x   = (const float*)d_in[0];
  const float* wq  = (const float*)d_in[1];
  const float* bq_ = (const float*)d_in[2];
  const float* wk  = (const float*)d_in[3];
  const float* bk_ = (const float*)d_in[4];
  const float* wv  = (const float*)d_in[5];
  const float* bv_ = (const float*)d_in[6];
  const float* wf  = (const float*)d_in[7];
  const float* bf_ = (const float*)d_in[8];
  (void)in_sizes; (void)n_in; (void)out_size; (void)ws_size;

  uint4* wfrag = (uint4*)d_ws;   // 4*16*2*4*64 frags * 16B = 512 KiB

  const int lds_bytes = 5 * 32 * 1024;   // 160 KB
  hipFuncSetAttribute(reinterpret_cast<const void*>(fused_pers9),
                      hipFuncAttributeMaxDynamicSharedMemorySize, lds_bytes);

  build_wfrag<<<128, 256, 0, stream>>>(wq, wk, wv, wf, wfrag);
  fused_pers9<<<NTOK / (NT * TILE), 1024, lds_bytes, stream>>>(
      x, bq_, bk_, bv_, bf_, wfrag, (float*)d_out);
}